// Round 5
// baseline (13651.891 us; speedup 1.0000x reference)
//
#include <hip/hip_runtime.h>

typedef unsigned int u32;
typedef unsigned short u16;
typedef short bf16x8 __attribute__((ext_vector_type(8)));
typedef float f32x4 __attribute__((ext_vector_type(4)));

#define TLEN 1000
#define BATCH 128
#define IDIM 64
#define HDIM 512

#define NWG 128
#define NTHR 256

// ws byte offsets
#define H0_OFF 0
#define H1_OFF 262144
#define BAR_OFF 524288
#define PX0_OFF 525312
#define PH0_OFF 721920
#define PX1_OFF 2294784
#define PH1_OFF 3867648

__device__ __forceinline__ u16 f2bf(float f) {
  u32 u = __float_as_uint(f);
  u += 0x7fffu + ((u >> 16) & 1u);
  return (u16)(u >> 16);
}
__device__ __forceinline__ float bf2f(u16 h) { return __uint_as_float(((u32)h) << 16); }
__device__ __forceinline__ float sigm(float x) { return 1.0f / (1.0f + __expf(-x)); }
__device__ __forceinline__ float tanhfast(float x) {
  float e = __expf(-2.0f * fabsf(x));
  float t = (1.0f - e) / (1.0f + e);
  return x >= 0.0f ? t : -t;
}

// ---------------- weight pre-pack into MFMA B-fragment order ----------------
__global__ void pack_weights(const float* Wih0, const float* Whh0,
                             const float* Wih1, const float* Whh1, char* ws) {
  int fid = blockIdx.x * NTHR + threadIdx.x;
  const float* src;
  int K, Kks;
  size_t obase;
  int f = fid;
  if (f < 12288) {
    src = Wih0; K = 64; Kks = 2; obase = PX0_OFF;
  } else if (f < 12288 + 98304) {
    f -= 12288; src = Whh0; K = 512; Kks = 16; obase = PH0_OFF;
  } else if (f < 12288 + 2 * 98304) {
    f -= 12288 + 98304; src = Wih1; K = 512; Kks = 16; obase = PX1_OFF;
  } else if (f < 12288 + 3 * 98304) {
    f -= 12288 + 2 * 98304; src = Whh1; K = 512; Kks = 16; obase = PH1_OFF;
  } else {
    return;
  }
  int lane = f & 63;
  int r = f >> 6;
  int ks = r % Kks; r /= Kks;
  int ct = r % 3;
  int sl = r / 3;
  int grow = ct * 512 + sl * 16 + (lane & 15);
  int k = ks * 32 + ((lane >> 4) * 8);
  const float* s = src + (size_t)grow * K + k;
  u32 p0 = f2bf(s[0]) | ((u32)f2bf(s[1]) << 16);
  u32 p1 = f2bf(s[2]) | ((u32)f2bf(s[3]) << 16);
  u32 p2 = f2bf(s[4]) | ((u32)f2bf(s[5]) << 16);
  u32 p3 = f2bf(s[6]) | ((u32)f2bf(s[7]) << 16);
  *(uint4*)(ws + obase + (size_t)f * 16) = make_uint4(p0, p1, p2, p3);
}

// ------- distributed group barrier: 64 monotonic slots, 64-lane parallel poll -------
__device__ __forceinline__ void fast_barrier(u32* slots, int wgl, u32 target) {
  __syncthreads();  // all waves done (vmcnt drained -> h stores left the CU)
  if (threadIdx.x == 0)
    __hip_atomic_store(slots + wgl, target, __ATOMIC_RELEASE, __HIP_MEMORY_SCOPE_AGENT);
  if (threadIdx.x < 64) {
    for (;;) {
      u32 v = __hip_atomic_load(slots + threadIdx.x, __ATOMIC_ACQUIRE,
                                __HIP_MEMORY_SCOPE_AGENT);
      if (__all(v >= target)) break;
      __builtin_amdgcn_s_sleep(1);
    }
  }
  __syncthreads();
}

struct KP {
  const float *x, *bih0, *bhh0, *bih1, *bhh1, *Wfc, *bfc;
  float* out;
  char* ws;
};

#define MFMA(A, B, C) __builtin_amdgcn_mfma_f32_16x16x32_bf16((A), (B), (C), 0, 0, 0)

// K=512 GEMM, A-frags straight from global (bf16 row-major [64][512] slab).
// Wave w owns ksteps j*4+w. One load = 16 rows x 64B contiguous (L2/LLC-hot).
__device__ __forceinline__ void gemm_direct(const u16* src, const bf16x8 B[3][4], int w,
                                            int lane, f32x4 a0[4], f32x4 a1[4], f32x4 a2[4]) {
#pragma unroll
  for (int j = 0; j < 4; ++j) {
    bf16x8 A[4];
#pragma unroll
    for (int rt = 0; rt < 4; ++rt)
      A[rt] = *(const bf16x8*)(src + (size_t)(rt * 16 + (lane & 15)) * HDIM +
                               (j * 4 + w) * 32 + ((lane >> 4) * 8));
#pragma unroll
    for (int rt = 0; rt < 4; ++rt) {
      a0[rt] = MFMA(A[rt], B[0][j], a0[rt]);
      a1[rt] = MFMA(A[rt], B[1][j], a1[rt]);
      a2[rt] = MFMA(A[rt], B[2][j], a2[rt]);
    }
  }
}

__global__ __launch_bounds__(NTHR, 1) void gru_main(KP P) {
  __shared__ f32x4 red[8][4][64];  // 32 KB cross-wave reduce (2-pass)
  const int tid = threadIdx.x;
  const int lane = tid & 63;
  const int w = tid >> 6;  // K-quarter (ksteps == w mod 4)
  const int id = blockIdx.x;
  const int bg = id >> 6;           // batch group: 0..1 (64 rows each)
  const int layer = (id >> 5) & 1;  // 0..1
  const int sl = id & 31;           // j-slice: 16 hidden cols
  const int wgl = id & 63;          // local wg id within batch group

  char* ws = P.ws;
  u16* h0 = (u16*)(ws + H0_OFF);
  u16* h1 = (u16*)(ws + H1_OFF);
  u32* slots = (u32*)(ws + BAR_OFF) + bg * 64;
  const bf16x8* px = (const bf16x8*)(ws + (layer ? PX1_OFF : PX0_OFF));
  const bf16x8* ph = (const bf16x8*)(ws + (layer ? PH1_OFF : PH0_OFF));

  const float* bih = layer ? P.bih1 : P.bih0;
  const float* bhh = layer ? P.bhh1 : P.bhh0;
  const int jj = sl * 16 + (lane & 15);
  const float b_r = bih[jj] + bhh[jj];
  const float b_z = bih[HDIM + jj] + bhh[HDIM + jj];
  const float b_nx = bih[2 * HDIM + jj];
  const float b_nh = bhh[2 * HDIM + jj];

  u16* hout = layer ? h1 : h0;
  const size_t bgoff = (size_t)bg * 64 * HDIM;

  // ---- persistent B fragments in registers: kstep = j*4 + w ----
  bf16x8 xB[3][4], hB[3][4];
#pragma unroll
  for (int ct = 0; ct < 3; ++ct)
#pragma unroll
    for (int j = 0; j < 4; ++j)
      hB[ct][j] = ph[((size_t)(sl * 3 + ct) * 16 + (j * 4 + w)) * 64 + lane];
  if (layer == 0) {
    const bf16x8 z8 = {0, 0, 0, 0, 0, 0, 0, 0};
#pragma unroll
    for (int ct = 0; ct < 3; ++ct)
#pragma unroll
      for (int j = 0; j < 4; ++j) xB[ct][j] = z8;
    if (w < 2) {
#pragma unroll
      for (int ct = 0; ct < 3; ++ct)
        xB[ct][0] = px[((size_t)(sl * 3 + ct) * 2 + w) * 64 + lane];
    }
  } else {
#pragma unroll
    for (int ct = 0; ct < 3; ++ct)
#pragma unroll
      for (int j = 0; j < 4; ++j)
        xB[ct][j] = px[((size_t)(sl * 3 + ct) * 16 + (j * 4 + w)) * 64 + lane];
  }

  const f32x4 zf = {0.f, 0.f, 0.f, 0.f};
  f32x4 hown = zf;

#pragma unroll 1
  for (int tick = 0; tick <= TLEN; ++tick) {
    const int p = tick & 1;
    const bool active = (layer == 0) ? (tick < TLEN) : (tick >= 1);
    if (active) {
      f32x4 aR[4], aZ[4], aXN[4], aHN[4];
#pragma unroll
      for (int rt = 0; rt < 4; ++rt) { aR[rt] = zf; aZ[rt] = zf; aXN[rt] = zf; aHN[rt] = zf; }
      const u16* h0src = h0 + (size_t)(1 - p) * BATCH * HDIM + bgoff;

      if (layer == 0) {
        // x-gemm from global fp32 (w<2), then recurrent h-gemm direct
        if (w < 2) {
#pragma unroll
          for (int rt = 0; rt < 4; ++rt) {
            const float* s = P.x +
                ((size_t)(bg * 64 + rt * 16 + (lane & 15)) * TLEN + tick) * IDIM +
                w * 32 + ((lane >> 4) * 8);
            float4 v0 = ((const float4*)s)[0];
            float4 v1 = ((const float4*)s)[1];
            bf16x8 A;
            A[0] = (short)f2bf(v0.x); A[1] = (short)f2bf(v0.y);
            A[2] = (short)f2bf(v0.z); A[3] = (short)f2bf(v0.w);
            A[4] = (short)f2bf(v1.x); A[5] = (short)f2bf(v1.y);
            A[6] = (short)f2bf(v1.z); A[7] = (short)f2bf(v1.w);
            aR[rt] = MFMA(A, xB[0][0], aR[rt]);
            aZ[rt] = MFMA(A, xB[1][0], aZ[rt]);
            aXN[rt] = MFMA(A, xB[2][0], aXN[rt]);
          }
        }
        gemm_direct(h0src, hB, w, lane, aR, aZ, aHN);
      } else {
        const u16* h1src = h1 + (size_t)(1 - p) * BATCH * HDIM + bgoff;
        gemm_direct(h0src, xB, w, lane, aR, aZ, aXN);  // x-input = h_seq0[t]
        gemm_direct(h1src, hB, w, lane, aR, aZ, aHN);  // recurrent
      }

      // ---- cross-wave K reduction, 2 passes of 32 KB ----
#pragma unroll
      for (int rt = 0; rt < 4; ++rt) {
        red[w * 2 + 0][rt][lane] = aR[rt];
        red[w * 2 + 1][rt][lane] = aZ[rt];
      }
      __syncthreads();
      f32x4 R = zf, Z = zf, XN = zf, HN = zf;
#pragma unroll
      for (int kq = 0; kq < 4; ++kq) {
        R = R + red[kq * 2 + 0][w][lane];
        Z = Z + red[kq * 2 + 1][w][lane];
      }
      __syncthreads();
#pragma unroll
      for (int rt = 0; rt < 4; ++rt) {
        red[w * 2 + 0][rt][lane] = aXN[rt];
        red[w * 2 + 1][rt][lane] = aHN[rt];
      }
      __syncthreads();
#pragma unroll
      for (int kq = 0; kq < 4; ++kq) {
        XN = XN + red[kq * 2 + 0][w][lane];
        HN = HN + red[kq * 2 + 1][w][lane];
      }
      // (no sync needed here: next SM write is after the barrier's syncthreads)

      // ---- gates + state update + store (wave w owns row-tile w) ----
      u16* hw = hout + (size_t)p * BATCH * HDIM;
#pragma unroll
      for (int q = 0; q < 4; ++q) {
        float r = sigm(R[q] + b_r);
        float z = sigm(Z[q] + b_z);
        float n = tanhfast(XN[q] + b_nx + r * (HN[q] + b_nh));
        float hv = (1.f - z) * n + z * hown[q];
        hown[q] = hv;
        int rowb = bg * 64 + w * 16 + (lane >> 4) * 4 + q;
        hw[(size_t)rowb * HDIM + jj] = f2bf(hv);
      }
    }
    fast_barrier(slots, wgl, (u32)(tick + 1));
  }

  // ---- final FC + sigmoid: hT1 = h1[parity 0] ----
  if (layer == 1 && sl == 0) {
    const u16* hT = h1;  // p=0 holds t=999
    int b = tid >> 2, qq = tid & 3;
    const u16* hr = hT + (size_t)(bg * 64 + b) * HDIM + qq * 128;
    const float* wf = P.Wfc + qq * 128;
    float s = 0.f;
#pragma unroll 4
    for (int k = 0; k < 128; ++k) s += bf2f(hr[k]) * wf[k];
    s += __shfl_xor(s, 1);
    s += __shfl_xor(s, 2);
    if (qq == 0) P.out[bg * 64 + b] = sigm(s + P.bfc[0]);
  }
}

extern "C" void kernel_launch(void* const* d_in, const int* in_sizes, int n_in,
                              void* d_out, int out_size, void* d_ws, size_t ws_size,
                              hipStream_t stream) {
  const float* x = (const float*)d_in[0];
  const float* Wih0 = (const float*)d_in[1];
  const float* Whh0 = (const float*)d_in[2];
  const float* bih0 = (const float*)d_in[3];
  const float* bhh0 = (const float*)d_in[4];
  const float* Wih1 = (const float*)d_in[5];
  const float* Whh1 = (const float*)d_in[6];
  const float* bih1 = (const float*)d_in[7];
  const float* bhh1 = (const float*)d_in[8];
  const float* Wfc = (const float*)d_in[9];
  const float* bfc = (const float*)d_in[10];

  hipMemsetAsync(d_ws, 0, BAR_OFF + 1024, stream);
  pack_weights<<<dim3(1200), dim3(NTHR), 0, stream>>>(Wih0, Whh0, Wih1, Whh1, (char*)d_ws);

  KP P = {x, bih0, bhh0, bih1, bhh1, Wfc, bfc, (float*)d_out, (char*)d_ws};
  void* args[] = {&P};
  hipError_t ce = hipLaunchCooperativeKernel((void*)gru_main, dim3(NWG), dim3(NTHR), args, 0,
                                             stream);
  if (ce != hipSuccess) {
    // co-residency trivially satisfied (128 WGs on 256 CUs, 32 KB LDS, 1 WG/CU);
    // the inter-WG barrier is hand-rolled atomics, so a plain launch is safe.
    (void)hipGetLastError();  // clear error state
    gru_main<<<dim3(NWG), dim3(NTHR), 0, stream>>>(P);
  }
}

// Round 6
// 7720.760 us; speedup vs baseline: 1.7682x; 1.7682x over previous
//
#include <hip/hip_runtime.h>

typedef unsigned int u32;
typedef unsigned short u16;
typedef short bf16x8 __attribute__((ext_vector_type(8)));
typedef float f32x4 __attribute__((ext_vector_type(4)));

#define TLEN 1000
#define BATCH 128
#define IDIM 64
#define HDIM 512

#define NWG 128
#define NTHR 256

// ws byte offsets
#define H0_OFF 0
#define H1_OFF 262144
#define BAR_OFF 524288
#define PX0_OFF 525312
#define PH0_OFF 721920
#define PX1_OFF 2294784
#define PH1_OFF 3867648

__device__ __forceinline__ u16 f2bf(float f) {
  u32 u = __float_as_uint(f);
  u += 0x7fffu + ((u >> 16) & 1u);
  return (u16)(u >> 16);
}
__device__ __forceinline__ float bf2f(u16 h) { return __uint_as_float(((u32)h) << 16); }
__device__ __forceinline__ float sigm(float x) { return 1.0f / (1.0f + __expf(-x)); }
__device__ __forceinline__ float tanhfast(float x) {
  float e = __expf(-2.0f * fabsf(x));
  float t = (1.0f - e) / (1.0f + e);
  return x >= 0.0f ? t : -t;
}

// ---- LLC-direct (L1+L2 bypass) memory ops: the ONLY cross-WG-visible traffic ----
__device__ __forceinline__ void llc_store16(u16* p, u32 v) {
  asm volatile("global_store_short %0, %1, off sc0 sc1" ::"v"(p), "v"(v) : "memory");
}
__device__ __forceinline__ void llc_store32(u32* p, u32 v) {
  asm volatile("global_store_dword %0, %1, off sc0 sc1" ::"v"(p), "v"(v) : "memory");
}
__device__ __forceinline__ u32 llc_load32(const u32* p) {
  u32 v;
  asm volatile("global_load_dword %0, %1, off sc0 sc1\n\ts_waitcnt vmcnt(0)"
               : "=v"(v) : "v"(p) : "memory");
  return v;
}
#define LLC_LOAD16(dst, p) \
  asm volatile("global_load_dwordx4 %0, %1, off sc0 sc1" : "=v"(dst) : "v"(p))

// ---------------- weight pre-pack into MFMA B-fragment order ----------------
__global__ void pack_weights(const float* Wih0, const float* Whh0,
                             const float* Wih1, const float* Whh1, char* ws) {
  int fid = blockIdx.x * NTHR + threadIdx.x;
  const float* src;
  int K, Kks;
  size_t obase;
  int f = fid;
  if (f < 12288) {
    src = Wih0; K = 64; Kks = 2; obase = PX0_OFF;
  } else if (f < 12288 + 98304) {
    f -= 12288; src = Whh0; K = 512; Kks = 16; obase = PH0_OFF;
  } else if (f < 12288 + 2 * 98304) {
    f -= 12288 + 98304; src = Wih1; K = 512; Kks = 16; obase = PX1_OFF;
  } else if (f < 12288 + 3 * 98304) {
    f -= 12288 + 2 * 98304; src = Whh1; K = 512; Kks = 16; obase = PH1_OFF;
  } else {
    return;
  }
  int lane = f & 63;
  int r = f >> 6;
  int ks = r % Kks; r /= Kks;
  int ct = r % 3;
  int sl = r / 3;
  int grow = ct * 512 + sl * 16 + (lane & 15);
  int k = ks * 32 + ((lane >> 4) * 8);
  const float* s = src + (size_t)grow * K + k;
  u32 p0 = f2bf(s[0]) | ((u32)f2bf(s[1]) << 16);
  u32 p1 = f2bf(s[2]) | ((u32)f2bf(s[3]) << 16);
  u32 p2 = f2bf(s[4]) | ((u32)f2bf(s[5]) << 16);
  u32 p3 = f2bf(s[6]) | ((u32)f2bf(s[7]) << 16);
  *(uint4*)(ws + obase + (size_t)f * 16) = make_uint4(p0, p1, p2, p3);
}

// ---- barrier: 64 monotonic slots; release = vmcnt drain + LLC slot store;
//      poll = 64-lane LLC loads, NO cache maintenance anywhere ----
__device__ __forceinline__ void fast_barrier(u32* slots, int wgl, u32 target) {
  __syncthreads();  // all waves' sc0sc1 h-stores drained (compiler emits vmcnt(0))
  if (threadIdx.x == 0) {
    asm volatile("s_waitcnt vmcnt(0)" ::: "memory");
    llc_store32(slots + wgl, target);
  }
  if (threadIdx.x < 64) {
    for (;;) {
      u32 v = llc_load32(slots + threadIdx.x);
      if (__all(v >= target)) break;
      __builtin_amdgcn_s_sleep(1);
    }
  }
  __syncthreads();
}

struct KP {
  const float *x, *bih0, *bhh0, *bih1, *bhh1, *Wfc, *bfc;
  float* out;
  char* ws;
};

#define MFMA(A, B, C) __builtin_amdgcn_mfma_f32_16x16x32_bf16((A), (B), (C), 0, 0, 0)

// K=512 GEMM, A-frags LLC-direct: issue 16 loads, one vmcnt(0), 48 MFMAs.
__device__ __forceinline__ void gemm_llc(const u16* src, const bf16x8 B[3][4], int w,
                                         int lane, f32x4 a0[4], f32x4 a1[4], f32x4 a2[4]) {
  bf16x8 A[4][4];
#pragma unroll
  for (int j = 0; j < 4; ++j)
#pragma unroll
    for (int rt = 0; rt < 4; ++rt) {
      const u16* p = src + (size_t)(rt * 16 + (lane & 15)) * HDIM + (j * 4 + w) * 32 +
                     ((lane >> 4) * 8);
      LLC_LOAD16(A[j][rt], p);
    }
  asm volatile("s_waitcnt vmcnt(0)" ::: "memory");
  __builtin_amdgcn_sched_barrier(0);
#pragma unroll
  for (int j = 0; j < 4; ++j)
#pragma unroll
    for (int rt = 0; rt < 4; ++rt) {
      a0[rt] = MFMA(A[j][rt], B[0][j], a0[rt]);
      a1[rt] = MFMA(A[j][rt], B[1][j], a1[rt]);
      a2[rt] = MFMA(A[j][rt], B[2][j], a2[rt]);
    }
}

__global__ __launch_bounds__(NTHR, 1) void gru_main(KP P) {
  __shared__ f32x4 red[8][4][64];  // 32 KB cross-wave reduce (2-pass)
  const int tid = threadIdx.x;
  const int lane = tid & 63;
  const int w = tid >> 6;  // K-quarter (ksteps == w mod 4)
  const int id = blockIdx.x;
  const int bg = id >> 6;           // batch group: 0..1 (64 rows each)
  const int layer = (id >> 5) & 1;  // 0..1
  const int sl = id & 31;           // j-slice: 16 hidden cols
  const int wgl = id & 63;          // local wg id within batch group

  char* ws = P.ws;
  u16* h0 = (u16*)(ws + H0_OFF);
  u16* h1 = (u16*)(ws + H1_OFF);
  u32* slots = (u32*)(ws + BAR_OFF) + bg * 64;
  const bf16x8* px = (const bf16x8*)(ws + (layer ? PX1_OFF : PX0_OFF));
  const bf16x8* ph = (const bf16x8*)(ws + (layer ? PH1_OFF : PH0_OFF));

  const float* bih = layer ? P.bih1 : P.bih0;
  const float* bhh = layer ? P.bhh1 : P.bhh0;
  const int jj = sl * 16 + (lane & 15);
  const float b_r = bih[jj] + bhh[jj];
  const float b_z = bih[HDIM + jj] + bhh[HDIM + jj];
  const float b_nx = bih[2 * HDIM + jj];
  const float b_nh = bhh[2 * HDIM + jj];

  u16* hout = layer ? h1 : h0;
  const size_t bgoff = (size_t)bg * 64 * HDIM;

  // ---- persistent B fragments in registers: kstep = j*4 + w ----
  bf16x8 xB[3][4], hB[3][4];
#pragma unroll
  for (int ct = 0; ct < 3; ++ct)
#pragma unroll
    for (int j = 0; j < 4; ++j)
      hB[ct][j] = ph[((size_t)(sl * 3 + ct) * 16 + (j * 4 + w)) * 64 + lane];
  if (layer == 0) {
    const bf16x8 z8 = {0, 0, 0, 0, 0, 0, 0, 0};
#pragma unroll
    for (int ct = 0; ct < 3; ++ct)
#pragma unroll
      for (int j = 0; j < 4; ++j) xB[ct][j] = z8;
    if (w < 2) {
#pragma unroll
      for (int ct = 0; ct < 3; ++ct)
        xB[ct][0] = px[((size_t)(sl * 3 + ct) * 2 + w) * 64 + lane];
    }
  } else {
#pragma unroll
    for (int ct = 0; ct < 3; ++ct)
#pragma unroll
      for (int j = 0; j < 4; ++j)
        xB[ct][j] = px[((size_t)(sl * 3 + ct) * 16 + (j * 4 + w)) * 64 + lane];
  }

  const f32x4 zf = {0.f, 0.f, 0.f, 0.f};
  f32x4 hown = zf;

#pragma unroll 1
  for (int tick = 0; tick <= TLEN; ++tick) {
    const int p = tick & 1;
    const bool active = (layer == 0) ? (tick < TLEN) : (tick >= 1);
    if (active) {
      f32x4 aR[4], aZ[4], aXN[4], aHN[4];
#pragma unroll
      for (int rt = 0; rt < 4; ++rt) { aR[rt] = zf; aZ[rt] = zf; aXN[rt] = zf; aHN[rt] = zf; }
      const u16* h0src = h0 + (size_t)(1 - p) * BATCH * HDIM + bgoff;

      if (layer == 0) {
        // x-gemm from plain-cached global fp32 (x is read-only; L2 stays warm now)
        if (w < 2) {
#pragma unroll
          for (int rt = 0; rt < 4; ++rt) {
            const float* s = P.x +
                ((size_t)(bg * 64 + rt * 16 + (lane & 15)) * TLEN + tick) * IDIM +
                w * 32 + ((lane >> 4) * 8);
            float4 v0 = ((const float4*)s)[0];
            float4 v1 = ((const float4*)s)[1];
            bf16x8 A;
            A[0] = (short)f2bf(v0.x); A[1] = (short)f2bf(v0.y);
            A[2] = (short)f2bf(v0.z); A[3] = (short)f2bf(v0.w);
            A[4] = (short)f2bf(v1.x); A[5] = (short)f2bf(v1.y);
            A[6] = (short)f2bf(v1.z); A[7] = (short)f2bf(v1.w);
            aR[rt] = MFMA(A, xB[0][0], aR[rt]);
            aZ[rt] = MFMA(A, xB[1][0], aZ[rt]);
            aXN[rt] = MFMA(A, xB[2][0], aXN[rt]);
          }
        }
        gemm_llc(h0src, hB, w, lane, aR, aZ, aHN);
      } else {
        const u16* h1src = h1 + (size_t)(1 - p) * BATCH * HDIM + bgoff;
        gemm_llc(h0src, xB, w, lane, aR, aZ, aXN);  // x-input = h_seq0[t]
        gemm_llc(h1src, hB, w, lane, aR, aZ, aHN);  // recurrent
      }

      // ---- cross-wave K reduction, 2 passes of 32 KB ----
#pragma unroll
      for (int rt = 0; rt < 4; ++rt) {
        red[w * 2 + 0][rt][lane] = aR[rt];
        red[w * 2 + 1][rt][lane] = aZ[rt];
      }
      __syncthreads();
      f32x4 R = zf, Z = zf, XN = zf, HN = zf;
#pragma unroll
      for (int kq = 0; kq < 4; ++kq) {
        R = R + red[kq * 2 + 0][w][lane];
        Z = Z + red[kq * 2 + 1][w][lane];
      }
      __syncthreads();
#pragma unroll
      for (int rt = 0; rt < 4; ++rt) {
        red[w * 2 + 0][rt][lane] = aXN[rt];
        red[w * 2 + 1][rt][lane] = aHN[rt];
      }
      __syncthreads();
#pragma unroll
      for (int kq = 0; kq < 4; ++kq) {
        XN = XN + red[kq * 2 + 0][w][lane];
        HN = HN + red[kq * 2 + 1][w][lane];
      }

      // ---- gates + state update + LLC-direct h store (wave w owns row-tile w) ----
      u16* hw = hout + (size_t)p * BATCH * HDIM;
#pragma unroll
      for (int q = 0; q < 4; ++q) {
        float r = sigm(R[q] + b_r);
        float z = sigm(Z[q] + b_z);
        float n = tanhfast(XN[q] + b_nx + r * (HN[q] + b_nh));
        float hv = (1.f - z) * n + z * hown[q];
        hown[q] = hv;
        int rowb = bg * 64 + w * 16 + (lane >> 4) * 4 + q;
        llc_store16(&hw[(size_t)rowb * HDIM + jj], (u32)f2bf(hv));
      }
    }
    fast_barrier(slots, wgl, (u32)(tick + 1));
  }

  // ---- final FC + sigmoid: hT1 = h1[parity 0] (plain loads: lines never cached stale) ----
  if (layer == 1 && sl == 0) {
    const u16* hT = h1;  // p=0 holds t=999
    int b = tid >> 2, qq = tid & 3;
    const u16* hr = hT + (size_t)(bg * 64 + b) * HDIM + qq * 128;
    const float* wf = P.Wfc + qq * 128;
    float s = 0.f;
#pragma unroll 4
    for (int k = 0; k < 128; ++k) s += bf2f(hr[k]) * wf[k];
    s += __shfl_xor(s, 1);
    s += __shfl_xor(s, 2);
    if (qq == 0) P.out[bg * 64 + b] = sigm(s + P.bfc[0]);
  }
}

extern "C" void kernel_launch(void* const* d_in, const int* in_sizes, int n_in,
                              void* d_out, int out_size, void* d_ws, size_t ws_size,
                              hipStream_t stream) {
  const float* x = (const float*)d_in[0];
  const float* Wih0 = (const float*)d_in[1];
  const float* Whh0 = (const float*)d_in[2];
  const float* bih0 = (const float*)d_in[3];
  const float* bhh0 = (const float*)d_in[4];
  const float* Wih1 = (const float*)d_in[5];
  const float* Whh1 = (const float*)d_in[6];
  const float* bih1 = (const float*)d_in[7];
  const float* bhh1 = (const float*)d_in[8];
  const float* Wfc = (const float*)d_in[9];
  const float* bfc = (const float*)d_in[10];

  hipMemsetAsync(d_ws, 0, BAR_OFF + 1024, stream);
  pack_weights<<<dim3(1200), dim3(NTHR), 0, stream>>>(Wih0, Whh0, Wih1, Whh1, (char*)d_ws);

  KP P = {x, bih0, bhh0, bih1, bhh1, Wfc, bfc, (float*)d_out, (char*)d_ws};
  void* args[] = {&P};
  hipError_t ce = hipLaunchCooperativeKernel((void*)gru_main, dim3(NWG), dim3(NTHR), args, 0,
                                             stream);
  if (ce != hipSuccess) {
    // co-residency trivially satisfied (128 WGs on 256 CUs, 32 KB LDS, 1 WG/CU);
    // the inter-WG barrier is hand-rolled atomics, so a plain launch is safe.
    (void)hipGetLastError();  // clear error state
    gru_main<<<dim3(NWG), dim3(NTHR), 0, stream>>>(P);
  }
}